// Round 1
// baseline (288.229 us; speedup 1.0000x reference)
//
#include <hip/hip_runtime.h>

typedef float f32x16 __attribute__((ext_vector_type(16)));
typedef short bf16x8 __attribute__((ext_vector_type(8)));

static __device__ __forceinline__ unsigned short f2bf(float f) {
  union { float f; unsigned int u; } v;
  v.f = f;
  return (unsigned short)((v.u + 0x7FFFu + ((v.u >> 16) & 1u)) >> 16);
}

// ---------------- weights: OIHW fp32 -> [tap][co][ci] bf16 ----------------
__global__ __launch_bounds__(256) void convert_weights(
    const float* __restrict__ W1, const float* __restrict__ W2,
    unsigned short* __restrict__ W1b, unsigned short* __restrict__ W2b) {
  int i = blockIdx.x * 256 + threadIdx.x;
  if (i < 9 * 128 * 256) {
    int tap = i >> 15;           // 32768 per tap
    int r = i & 32767;
    int co = r >> 8, ci = r & 255;
    W1b[i] = f2bf(W1[(co * 256 + ci) * 9 + tap]);
  } else {
    int j = i - 9 * 128 * 256;
    if (j < 9 * 128 * 128) {
      int tap = j >> 14;         // 16384 per tap
      int r = j & 16383;
      int co = r >> 7, ci = r & 127;
      W2b[j] = f2bf(W2[(co * 128 + ci) * 9 + tap]);
    }
  }
}

// ---------------- NCHW fp32 row -> NHWC bf16 (one (b,y) row per block) ----
__global__ __launch_bounds__(256) void transpose_to_bf16(
    const float* __restrict__ src,     // [8,128,128,128] NCHW
    unsigned short* __restrict__ dst,  // [row][px][roww] bf16
    int roww, int coff) {
  int row = blockIdx.x;                // b*128 + y
  int b = row >> 7, y = row & 127;
  const float* s = src + (long)b * 128 * 16384 + (long)y * 128;
  unsigned short* d = dst + (long)row * 128 * roww + coff;
  for (int it = 0; it < 8; ++it) {
    int u = it * 256 + (int)threadIdx.x;  // cig(16) x px(128)
    int cig = u >> 7;
    int px = u & 127;
    unsigned short pk[8];
#pragma unroll
    for (int e = 0; e < 8; ++e)
      pk[e] = f2bf(s[(long)(cig * 8 + e) * 16384 + px]);
    uint4 vv;
    vv.x = (unsigned)pk[0] | ((unsigned)pk[1] << 16);
    vv.y = (unsigned)pk[2] | ((unsigned)pk[3] << 16);
    vv.z = (unsigned)pk[4] | ((unsigned)pk[5] << 16);
    vv.w = (unsigned)pk[6] | ((unsigned)pk[7] << 16);
    *(uint4*)(&d[(long)px * roww + cig * 8]) = vv;
  }
}

// ---------------- 3x3 SAME conv, implicit GEMM, bf16 MFMA -----------------
// block = one (b,y) row: 128 px x 128 co.  4 waves = 2(co) x 2(px), each
// wave 64co x 64px of 32x32x16 MFMAs.  K = taps(9) x ci, staged 16 ci/chunk.
template <int CIN, bool OUT_NCHW>
__global__ __launch_bounds__(256) void conv3x3(
    const unsigned short* __restrict__ src,  // NHWC bf16 [8,128,128,CIN]
    const unsigned short* __restrict__ wt,   // [9][128][CIN] bf16
    const float* __restrict__ bias,          // [128]
    unsigned short* __restrict__ dst_bf16,   // NHWC bf16 [8,128,128,128]
    float* __restrict__ dst_f32) {           // NCHW fp32 [8,128,128,128]
  __shared__ unsigned short in_tile[3 * 130 * 16];  // [yy][xxl][ci16] 12.2KB
  __shared__ unsigned short wt_tile[9 * 128 * 16];  // [tap][co][ci16] 36KB
  __shared__ float sb[128];

  const int tid = threadIdx.x;
  const int row = blockIdx.x;
  const int b = row >> 7, y = row & 127;
  const int lane = tid & 63, wave = tid >> 6;
  const int wco = wave >> 1, wpx = wave & 1;
  const int l31 = lane & 31, kh = lane >> 5;

  if (tid < 128) sb[tid] = bias[tid];

  f32x16 acc[2][2] = {};

  for (int cic = 0; cic < CIN / 16; ++cic) {
    __syncthreads();
    // stage input halo tile (zeros outside the image)
#pragma unroll
    for (int it = 0; it < 4; ++it) {
      int T = it * 256 + tid;       // 780 16B slots
      int pos = T >> 1, half = T & 1;
      int yy = pos / 130;
      int xxl = pos - yy * 130;     // global x + 1
      int gy = y + yy - 1;
      uint4 v; v.x = 0; v.y = 0; v.z = 0; v.w = 0;
      if ((T < 780) && (xxl >= 1) && (xxl <= 128) && (gy >= 0) && (gy < 128))
        v = *(const uint4*)(src + ((long)(b * 128 + gy) * 128 + (xxl - 1)) * CIN +
                            cic * 16 + half * 8);
      if (T < 780) *(uint4*)(&in_tile[(size_t)T * 8]) = v;
    }
    // stage weight tile: [tap][co][16]
#pragma unroll
    for (int it = 0; it < 9; ++it) {
      uint4 v = *(const uint4*)(wt + (long)(it * 128 + (tid >> 1)) * CIN +
                                cic * 16 + (tid & 1) * 8);
      *(uint4*)(&wt_tile[((size_t)(it * 256 + tid)) * 8]) = v;
    }
    __syncthreads();

#pragma unroll
    for (int ky = 0; ky < 3; ++ky) {
#pragma unroll
      for (int kx = 0; kx < 3; ++kx) {
        const int t = ky * 3 + kx;
        bf16x8 a0 = *(const bf16x8*)(&wt_tile[(size_t)((t * 128 + wco * 64 + l31) * 16 + kh * 8)]);
        bf16x8 a1 = *(const bf16x8*)(&wt_tile[(size_t)((t * 128 + wco * 64 + 32 + l31) * 16 + kh * 8)]);
        bf16x8 b0 = *(const bf16x8*)(&in_tile[(size_t)((ky * 130 + wpx * 64 + l31 + kx) * 16 + kh * 8)]);
        bf16x8 b1 = *(const bf16x8*)(&in_tile[(size_t)((ky * 130 + wpx * 64 + 32 + l31 + kx) * 16 + kh * 8)]);
        acc[0][0] = __builtin_amdgcn_mfma_f32_32x32x16_bf16(a0, b0, acc[0][0], 0, 0, 0);
        acc[0][1] = __builtin_amdgcn_mfma_f32_32x32x16_bf16(a0, b1, acc[0][1], 0, 0, 0);
        acc[1][0] = __builtin_amdgcn_mfma_f32_32x32x16_bf16(a1, b0, acc[1][0], 0, 0, 0);
        acc[1][1] = __builtin_amdgcn_mfma_f32_32x32x16_bf16(a1, b1, acc[1][1], 0, 0, 0);
      }
    }
  }

  // epilogue: bias + leaky, D layout col(px)=lane&31, row(co)=(r&3)+8*(r>>2)+4*kh
#pragma unroll
  for (int fc = 0; fc < 2; ++fc) {
#pragma unroll
    for (int fp = 0; fp < 2; ++fp) {
      const int px = wpx * 64 + fp * 32 + l31;
      if constexpr (!OUT_NCHW) {
#pragma unroll
        for (int rg = 0; rg < 4; ++rg) {
          const int co0 = wco * 64 + fc * 32 + rg * 8 + kh * 4;
          unsigned short pk[4];
#pragma unroll
          for (int q = 0; q < 4; ++q) {
            float v = acc[fc][fp][rg * 4 + q] + sb[co0 + q];
            v = v > 0.f ? v : 0.01f * v;
            pk[q] = f2bf(v);
          }
          uint2 o;
          o.x = (unsigned)pk[0] | ((unsigned)pk[1] << 16);
          o.y = (unsigned)pk[2] | ((unsigned)pk[3] << 16);
          *(uint2*)(&dst_bf16[((long)row * 128 + px) * 128 + co0]) = o;
        }
      } else {
#pragma unroll
        for (int r = 0; r < 16; ++r) {
          const int co = wco * 64 + fc * 32 + (r & 3) + 8 * (r >> 2) + 4 * kh;
          float v = acc[fc][fp][r] + sb[co];
          v = v > 0.f ? v : 0.01f * v;
          dst_f32[((long)(b * 128 + co) << 14) + (y << 7) + px] = v;
        }
      }
    }
  }
}

// ---------------- 1x1 conv to 2 classes + entropy map + unob --------------
__global__ __launch_bounds__(128) void ds_amap(
    const float* __restrict__ h,    // [8,128,128,128] NCHW
    const float* __restrict__ wds,  // [2,128]
    const int* __restrict__ tar,    // [8,128,128]
    float* __restrict__ ds,         // [8,2,128,128]
    float* __restrict__ amap) {     // [8,128,128]
  __shared__ float w0[128], w1[128];
  int row = blockIdx.x;
  int b = row >> 7, y = row & 127;
  int px = threadIdx.x;
  w0[px] = wds[px];
  w1[px] = wds[128 + px];
  __syncthreads();
  const float* hp = h + (long)b * 128 * 16384 + y * 128 + px;
  float a0 = 0.f, a1 = 0.f;
#pragma unroll 16
  for (int c = 0; c < 128; ++c) {
    float v = hp[(long)c * 16384];
    a0 += w0[c] * v;
    a1 += w1[c] * v;
  }
  ds[((long)b * 2) * 16384 + y * 128 + px] = a0;
  ds[((long)b * 2 + 1) * 16384 + y * 128 + px] = a1;
  float m = fmaxf(a0, a1);
  float e0 = expf(a0 - m), e1 = expf(a1 - m);
  float s = e0 + e1;
  float p0 = e0 / s, p1 = e1 / s;
  float ent = -(p0 * log2f(p0 + 1e-6f) + p1 * log2f(p1 + 1e-6f));
  float un = ent >= 0.001f ? 1.f : 0.f;
  float pro = 1.f;
  const int* tb = tar + (long)b * 16384;
  if (y > 0 && y < 127 && px > 0 && px < 127) {
    int c = tb[y * 128 + px];
    if (c != 0) {
      int nb = tb[(y - 1) * 128 + px] + tb[(y + 1) * 128 + px] +
               tb[y * 128 + px - 1] + tb[y * 128 + px + 1];
      if (4 * c != nb) pro = 0.f;
    }
  }
  amap[(long)row * 128 + px] = un * pro;
}

extern "C" void kernel_launch(void* const* d_in, const int* in_sizes, int n_in,
                              void* d_out, int out_size, void* d_ws, size_t ws_size,
                              hipStream_t stream) {
  const float* x    = (const float*)d_in[0];
  const float* skip = (const float*)d_in[1];
  const int*   tar  = (const int*)d_in[2];
  const float* W1   = (const float*)d_in[3];
  const float* b1   = (const float*)d_in[4];
  const float* W2   = (const float*)d_in[5];
  const float* b2   = (const float*)d_in[6];
  const float* Wds  = (const float*)d_in[7];

  float* out_h  = (float*)d_out;            // 16777216 f32 (h, NCHW)
  float* out_ds = out_h + 16777216;         // 262144 f32
  float* out_am = out_ds + 262144;          // 131072 f32

  // workspace: W1b | W2b | (1MB align) h1
  unsigned short* W1b = (unsigned short*)d_ws;            // 294912 elems
  unsigned short* W2b = W1b + 294912;                     // 147456 elems
  unsigned short* h1  = (unsigned short*)((char*)d_ws + (1u << 20));  // 16.7M elems

  // h0 (concat(x,skip) as NHWC bf16, 67.1MB) lives in d_out; it is fully
  // dead before conv2 overwrites d_out with h.
  unsigned short* h0 = (unsigned short*)d_out;

  convert_weights<<<1728, 256, 0, stream>>>(W1, W2, W1b, W2b);
  transpose_to_bf16<<<1024, 256, 0, stream>>>(x, h0, 256, 0);
  transpose_to_bf16<<<1024, 256, 0, stream>>>(skip, h0, 256, 128);
  conv3x3<256, false><<<1024, 256, 0, stream>>>(h0, W1b, b1, h1, nullptr);
  conv3x3<128, true><<<1024, 256, 0, stream>>>(h1, W2b, b2, nullptr, out_h);
  ds_amap<<<1024, 128, 0, stream>>>(out_h, Wds, tar, out_ds, out_am);
}

// Round 2
// 285.791 us; speedup vs baseline: 1.0085x; 1.0085x over previous
//
#include <hip/hip_runtime.h>

typedef float f32x16 __attribute__((ext_vector_type(16)));
typedef short bf16x8 __attribute__((ext_vector_type(8)));

static __device__ __forceinline__ unsigned short f2bf(float f) {
  union { float f; unsigned int u; } v;
  v.f = f;
  return (unsigned short)((v.u + 0x7FFFu + ((v.u >> 16) & 1u)) >> 16);
}

// ---------------- weights: OIHW fp32 -> [tap][co][ci] bf16 ----------------
__global__ __launch_bounds__(256) void convert_weights(
    const float* __restrict__ W1, const float* __restrict__ W2,
    unsigned short* __restrict__ W1b, unsigned short* __restrict__ W2b) {
  int i = blockIdx.x * 256 + threadIdx.x;
  if (i < 9 * 128 * 256) {
    int tap = i >> 15;           // 32768 per tap
    int r = i & 32767;
    int co = r >> 8, ci = r & 255;
    W1b[i] = f2bf(W1[(co * 256 + ci) * 9 + tap]);
  } else {
    int j = i - 9 * 128 * 256;
    if (j < 9 * 128 * 128) {
      int tap = j >> 14;         // 16384 per tap
      int r = j & 16383;
      int co = r >> 7, ci = r & 127;
      W2b[j] = f2bf(W2[(co * 128 + ci) * 9 + tap]);
    }
  }
}

// ---------------- NCHW fp32 row -> NHWC bf16 (one (b,y) row per block) ----
__global__ __launch_bounds__(256) void transpose_to_bf16(
    const float* __restrict__ src,     // [8,128,128,128] NCHW
    unsigned short* __restrict__ dst,  // [row][px][roww] bf16
    int roww, int coff) {
  int row = blockIdx.x;                // b*128 + y
  int b = row >> 7, y = row & 127;
  const float* s = src + (long)b * 128 * 16384 + (long)y * 128;
  unsigned short* d = dst + (long)row * 128 * roww + coff;
  for (int it = 0; it < 8; ++it) {
    int u = it * 256 + (int)threadIdx.x;  // cig(16) x px(128)
    int cig = u >> 7;
    int px = u & 127;
    unsigned short pk[8];
#pragma unroll
    for (int e = 0; e < 8; ++e)
      pk[e] = f2bf(s[(long)(cig * 8 + e) * 16384 + px]);
    uint4 vv;
    vv.x = (unsigned)pk[0] | ((unsigned)pk[1] << 16);
    vv.y = (unsigned)pk[2] | ((unsigned)pk[3] << 16);
    vv.z = (unsigned)pk[4] | ((unsigned)pk[5] << 16);
    vv.w = (unsigned)pk[6] | ((unsigned)pk[7] << 16);
    *(uint4*)(&d[(long)px * roww + cig * 8]) = vv;
  }
}

// ---------------- 3x3 SAME conv, implicit GEMM, bf16 MFMA -----------------
// block = one (b,y) row: 128 px x 128 co.  4 waves = 2(co) x 2(px), each
// wave 64co x 64px of 32x32x16 MFMAs.  K = taps(9) x ci, staged 16 ci/chunk.
//
// LDS layout: "plane-split" — each 16-ci row is split into its two 16B
// halves (kh-planes), each plane row-contiguous (16B per row-slot). A wave's
// ds_read_b128 then has 32 consecutive lanes reading 32 CONSECUTIVE 16B
// chunks -> bank-conflict-free for both A and B frags and for staging writes.
#define PLI 392   // in-plane row slots (3*130=390, padded to keep planes 128B-aligned)
#define PLW 1152  // wt-plane row slots (9*128)
template <int CIN, bool OUT_NCHW>
__global__ __launch_bounds__(256) void conv3x3(
    const unsigned short* __restrict__ src,  // NHWC bf16 [8,128,128,CIN]
    const unsigned short* __restrict__ wt,   // [9][128][CIN] bf16
    const float* __restrict__ bias,          // [128]
    unsigned short* __restrict__ dst_bf16,   // NHWC bf16 [8,128,128,128]
    float* __restrict__ dst_f32) {           // NCHW fp32 [8,128,128,128]
  __shared__ unsigned short in_tile[2 * PLI * 8];  // 12.5KB
  __shared__ unsigned short wt_tile[2 * PLW * 8];  // 36KB
  __shared__ float sb[128];

  const int tid = threadIdx.x;
  const int row = blockIdx.x;
  const int b = row >> 7, y = row & 127;
  const int lane = tid & 63, wave = tid >> 6;
  const int wco = wave >> 1, wpx = wave & 1;
  const int l31 = lane & 31, kh = lane >> 5;

  if (tid < 128) sb[tid] = bias[tid];

  f32x16 acc[2][2] = {};

  for (int cic = 0; cic < CIN / 16; ++cic) {
    __syncthreads();
    // stage input halo tile (zeros outside the image)
#pragma unroll
    for (int it = 0; it < 4; ++it) {
      int T = it * 256 + tid;       // 780 16B slots
      int pos = T >> 1, half = T & 1;
      int yy = pos / 130;
      int xxl = pos - yy * 130;     // global x + 1
      int gy = y + yy - 1;
      uint4 v; v.x = 0; v.y = 0; v.z = 0; v.w = 0;
      if ((T < 780) && (xxl >= 1) && (xxl <= 128) && (gy >= 0) && (gy < 128))
        v = *(const uint4*)(src + ((long)(b * 128 + gy) * 128 + (xxl - 1)) * CIN +
                            cic * 16 + half * 8);
      if (T < 780) *(uint4*)(&in_tile[(size_t)(half * PLI + pos) * 8]) = v;
    }
    // stage weight tile: row = tap*128+co, plane = half
#pragma unroll
    for (int it = 0; it < 9; ++it) {
      uint4 v = *(const uint4*)(wt + (long)(it * 128 + (tid >> 1)) * CIN +
                                cic * 16 + (tid & 1) * 8);
      *(uint4*)(&wt_tile[(size_t)((tid & 1) * PLW + it * 128 + (tid >> 1)) * 8]) = v;
    }
    __syncthreads();

    const size_t wbase = (size_t)(kh * PLW) * 8;
    const size_t ibase = (size_t)(kh * PLI) * 8;
#pragma unroll
    for (int ky = 0; ky < 3; ++ky) {
#pragma unroll
      for (int kx = 0; kx < 3; ++kx) {
        const int t = ky * 3 + kx;
        bf16x8 a0 = *(const bf16x8*)(&wt_tile[wbase + (size_t)(t * 128 + wco * 64 + l31) * 8]);
        bf16x8 a1 = *(const bf16x8*)(&wt_tile[wbase + (size_t)(t * 128 + wco * 64 + 32 + l31) * 8]);
        bf16x8 b0 = *(const bf16x8*)(&in_tile[ibase + (size_t)(ky * 130 + wpx * 64 + l31 + kx) * 8]);
        bf16x8 b1 = *(const bf16x8*)(&in_tile[ibase + (size_t)(ky * 130 + wpx * 64 + 32 + l31 + kx) * 8]);
        acc[0][0] = __builtin_amdgcn_mfma_f32_32x32x16_bf16(a0, b0, acc[0][0], 0, 0, 0);
        acc[0][1] = __builtin_amdgcn_mfma_f32_32x32x16_bf16(a0, b1, acc[0][1], 0, 0, 0);
        acc[1][0] = __builtin_amdgcn_mfma_f32_32x32x16_bf16(a1, b0, acc[1][0], 0, 0, 0);
        acc[1][1] = __builtin_amdgcn_mfma_f32_32x32x16_bf16(a1, b1, acc[1][1], 0, 0, 0);
      }
    }
  }

  // epilogue: bias + leaky, D layout col(px)=lane&31, row(co)=(r&3)+8*(r>>2)+4*kh
#pragma unroll
  for (int fc = 0; fc < 2; ++fc) {
#pragma unroll
    for (int fp = 0; fp < 2; ++fp) {
      const int px = wpx * 64 + fp * 32 + l31;
      if constexpr (!OUT_NCHW) {
#pragma unroll
        for (int rg = 0; rg < 4; ++rg) {
          const int co0 = wco * 64 + fc * 32 + rg * 8 + kh * 4;
          unsigned short pk[4];
#pragma unroll
          for (int q = 0; q < 4; ++q) {
            float v = acc[fc][fp][rg * 4 + q] + sb[co0 + q];
            v = v > 0.f ? v : 0.01f * v;
            pk[q] = f2bf(v);
          }
          uint2 o;
          o.x = (unsigned)pk[0] | ((unsigned)pk[1] << 16);
          o.y = (unsigned)pk[2] | ((unsigned)pk[3] << 16);
          *(uint2*)(&dst_bf16[((long)row * 128 + px) * 128 + co0]) = o;
        }
      } else {
#pragma unroll
        for (int r = 0; r < 16; ++r) {
          const int co = wco * 64 + fc * 32 + (r & 3) + 8 * (r >> 2) + 4 * kh;
          float v = acc[fc][fp][r] + sb[co];
          v = v > 0.f ? v : 0.01f * v;
          dst_f32[((long)(b * 128 + co) << 14) + (y << 7) + px] = v;
        }
      }
    }
  }
}

// ---------------- 1x1 conv to 2 classes + entropy map + unob --------------
__global__ __launch_bounds__(128) void ds_amap(
    const float* __restrict__ h,    // [8,128,128,128] NCHW
    const float* __restrict__ wds,  // [2,128]
    const int* __restrict__ tar,    // [8,128,128]
    float* __restrict__ ds,         // [8,2,128,128]
    float* __restrict__ amap) {     // [8,128,128]
  __shared__ float w0[128], w1[128];
  int row = blockIdx.x;
  int b = row >> 7, y = row & 127;
  int px = threadIdx.x;
  w0[px] = wds[px];
  w1[px] = wds[128 + px];
  __syncthreads();
  const float* hp = h + (long)b * 128 * 16384 + y * 128 + px;
  float a0 = 0.f, a1 = 0.f;
#pragma unroll 16
  for (int c = 0; c < 128; ++c) {
    float v = hp[(long)c * 16384];
    a0 += w0[c] * v;
    a1 += w1[c] * v;
  }
  ds[((long)b * 2) * 16384 + y * 128 + px] = a0;
  ds[((long)b * 2 + 1) * 16384 + y * 128 + px] = a1;
  float m = fmaxf(a0, a1);
  float e0 = expf(a0 - m), e1 = expf(a1 - m);
  float s = e0 + e1;
  float p0 = e0 / s, p1 = e1 / s;
  float ent = -(p0 * log2f(p0 + 1e-6f) + p1 * log2f(p1 + 1e-6f));
  float un = ent >= 0.001f ? 1.f : 0.f;
  float pro = 1.f;
  const int* tb = tar + (long)b * 16384;
  if (y > 0 && y < 127 && px > 0 && px < 127) {
    int c = tb[y * 128 + px];
    if (c != 0) {
      int nb = tb[(y - 1) * 128 + px] + tb[(y + 1) * 128 + px] +
               tb[y * 128 + px - 1] + tb[y * 128 + px + 1];
      if (4 * c != nb) pro = 0.f;
    }
  }
  amap[(long)row * 128 + px] = un * pro;
}

extern "C" void kernel_launch(void* const* d_in, const int* in_sizes, int n_in,
                              void* d_out, int out_size, void* d_ws, size_t ws_size,
                              hipStream_t stream) {
  const float* x    = (const float*)d_in[0];
  const float* skip = (const float*)d_in[1];
  const int*   tar  = (const int*)d_in[2];
  const float* W1   = (const float*)d_in[3];
  const float* b1   = (const float*)d_in[4];
  const float* W2   = (const float*)d_in[5];
  const float* b2   = (const float*)d_in[6];
  const float* Wds  = (const float*)d_in[7];

  float* out_h  = (float*)d_out;            // 16777216 f32 (h, NCHW)
  float* out_ds = out_h + 16777216;         // 262144 f32
  float* out_am = out_ds + 262144;          // 131072 f32

  // workspace: W1b | W2b | (1MB align) h1
  unsigned short* W1b = (unsigned short*)d_ws;            // 294912 elems
  unsigned short* W2b = W1b + 294912;                     // 147456 elems
  unsigned short* h1  = (unsigned short*)((char*)d_ws + (1u << 20));  // 16.7M elems

  // h0 (concat(x,skip) as NHWC bf16, 67.1MB) lives in d_out; it is fully
  // dead before conv2 overwrites d_out with h.
  unsigned short* h0 = (unsigned short*)d_out;

  convert_weights<<<1728, 256, 0, stream>>>(W1, W2, W1b, W2b);
  transpose_to_bf16<<<1024, 256, 0, stream>>>(x, h0, 256, 0);
  transpose_to_bf16<<<1024, 256, 0, stream>>>(skip, h0, 256, 128);
  conv3x3<256, false><<<1024, 256, 0, stream>>>(h0, W1b, b1, h1, nullptr);
  conv3x3<128, true><<<1024, 256, 0, stream>>>(h1, W2b, b2, nullptr, out_h);
  ds_amap<<<1024, 128, 0, stream>>>(out_h, Wds, tar, out_ds, out_am);
}

// Round 3
// 266.753 us; speedup vs baseline: 1.0805x; 1.0714x over previous
//
#include <hip/hip_runtime.h>

typedef float f32x16 __attribute__((ext_vector_type(16)));
typedef short bf16x8 __attribute__((ext_vector_type(8)));
typedef unsigned int u32;

static __device__ __forceinline__ unsigned short f2bf(float f) {
  union { float f; unsigned int u; } v;
  v.f = f;
  return (unsigned short)((v.u + 0x7FFFu + ((v.u >> 16) & 1u)) >> 16);
}

// async 16B global->LDS (DMA, no VGPR round trip). LDS dest = uniform base,
// lane i writes chunk base+i*16. Global src is per-lane.
static __device__ __forceinline__ void gl_lds16(const unsigned short* g,
                                                unsigned short* l) {
  __builtin_amdgcn_global_load_lds(
      (const __attribute__((address_space(1))) u32*)g,
      (__attribute__((address_space(3))) u32*)l, 16, 0, 0);
}

// ---------------- weights: OIHW fp32 -> [tap][co][ci] bf16; +zero page ----
__global__ __launch_bounds__(256) void convert_weights(
    const float* __restrict__ W1, const float* __restrict__ W2,
    unsigned short* __restrict__ W1b, unsigned short* __restrict__ W2b,
    unsigned short* __restrict__ zp) {
  if (blockIdx.x == 1728) {  // zero the 8KB zero page
    uint4* z = (uint4*)zp;
    z[threadIdx.x] = make_uint4(0, 0, 0, 0);
    z[256 + threadIdx.x] = make_uint4(0, 0, 0, 0);
    return;
  }
  int i = blockIdx.x * 256 + threadIdx.x;
  if (i < 9 * 128 * 256) {
    int tap = i >> 15;
    int r = i & 32767;
    int co = r >> 8, ci = r & 255;
    W1b[i] = f2bf(W1[(co * 256 + ci) * 9 + tap]);
  } else {
    int j = i - 9 * 128 * 256;
    if (j < 9 * 128 * 128) {
      int tap = j >> 14;
      int r = j & 16383;
      int co = r >> 7, ci = r & 127;
      W2b[j] = f2bf(W2[(co * 128 + ci) * 9 + tap]);
    }
  }
}

// -------- NCHW fp32 row -> padded NHWC bf16 [8][128][130][256] ------------
__global__ __launch_bounds__(256) void transpose_to_bf16(
    const float* __restrict__ src, unsigned short* __restrict__ dst, int coff) {
  int row = blockIdx.x;  // b*128+y
  int b = row >> 7, y = row & 127;
  const float* s = src + (long)b * 128 * 16384 + (long)y * 128;
  unsigned short* d = dst + ((long)row * 130 + 1) * 256 + coff;
  for (int it = 0; it < 8; ++it) {
    int u = it * 256 + (int)threadIdx.x;
    int cig = u >> 7, px = u & 127;
    unsigned short pk[8];
#pragma unroll
    for (int e = 0; e < 8; ++e)
      pk[e] = f2bf(s[(long)(cig * 8 + e) * 16384 + px]);
    uint4 vv;
    vv.x = (unsigned)pk[0] | ((unsigned)pk[1] << 16);
    vv.y = (unsigned)pk[2] | ((unsigned)pk[3] << 16);
    vv.z = (unsigned)pk[4] | ((unsigned)pk[5] << 16);
    vv.w = (unsigned)pk[6] | ((unsigned)pk[7] << 16);
    *(uint4*)(&d[(long)px * 256 + cig * 8]) = vv;
  }
  if (coff == 0 && threadIdx.x < 64) {  // zero x-pad columns 0 and 129
    int colsel = threadIdx.x >> 5, k = threadIdx.x & 31;
    long col = colsel * 129L;
    *(uint4*)(&dst[((long)row * 130 + col) * 256 + k * 8]) = make_uint4(0, 0, 0, 0);
  }
}

// ---------------- 3x3 SAME conv, implicit GEMM, bf16 MFMA -----------------
// block = 2 image rows: 256 px x 128 co, 8 waves (wco 2 x wpx 4).
// K staged 16 ci/chunk into plane-split LDS via global_load_lds (linear dest,
// per-lane global src on width-130 pre-padded NHWC input; y-OOB -> zero page).
#define IPL 520   // in-tile slots/plane (4 halo rows x 130)
#define WPL 1152  // wt-tile slots/plane (9 taps x 128 co)
template <int CIN, bool OUT_NCHW>
__global__ __launch_bounds__(512) void conv3x3(
    const unsigned short* __restrict__ src,  // padded NHWC [8][128][130][CIN]
    const unsigned short* __restrict__ wt,   // [9][128][CIN] bf16
    const float* __restrict__ bias,          // [128]
    const unsigned short* __restrict__ zp,   // zeroed 8KB
    unsigned short* __restrict__ dst_bf16,   // padded NHWC [8][128][130][128]
    float* __restrict__ dst_f32) {           // NCHW fp32 [8,128,128,128]
  __shared__ unsigned short in_tile[2 * IPL * 8];  // 16.6KB
  __shared__ unsigned short wt_tile[2 * WPL * 8];  // 36.9KB
  __shared__ float sb[128];

  const int tid = threadIdx.x;
  const int b = blockIdx.x >> 6;
  const int y0 = (blockIdx.x & 63) * 2;
  const int lane = tid & 63, wave = tid >> 6;
  const int wco = wave & 1, wpx = wave >> 1;
  const int l31 = lane & 31, kh = lane >> 5;
  const int rowoff = wpx >> 1, p0 = (wpx & 1) * 64;

  if (tid < 128) sb[tid] = bias[tid];

  f32x16 acc[2][2] = {};

  for (int cic = 0; cic < CIN / 16; ++cic) {
    __syncthreads();
    // ---- input bulk: 1024 chunks (2 planes x 4 rows x 128 px), 2 ops/wave
#pragma unroll
    for (int j = 0; j < 2; ++j) {
      int C = wave * 128 + j * 64;
      int p = C >> 9, r = C & 511;
      int hy = r >> 7, hx0 = r & 127;
      int gy = y0 - 1 + hy;
      const unsigned short* g =
          (gy >= 0 && gy < 128)
              ? src + ((long)(b * 128 + gy) * 130 + hx0 + lane) * CIN + cic * 16 + p * 8
              : zp + lane * 8;
      gl_lds16(g, &in_tile[(size_t)(p * IPL + hy * 130 + hx0) * 8]);
    }
    // ---- input tail: hx 128,129 (16 chunks), reg-staged
    if (tid < 16) {
      int p = tid >> 3, rr = tid & 7;
      int hy = rr >> 1, hx = 128 + (rr & 1);
      int gy = y0 - 1 + hy;
      uint4 v = make_uint4(0, 0, 0, 0);
      if (gy >= 0 && gy < 128)
        v = *(const uint4*)(src + ((long)(b * 128 + gy) * 130 + hx) * CIN +
                            cic * 16 + p * 8);
      *(uint4*)(&in_tile[(size_t)(p * IPL + hy * 130 + hx) * 8]) = v;
    }
    // ---- weights: 2304 chunks = 36 ops, round-robin over waves
    for (int o = wave; o < 36; o += 8) {
      int p = o / 18, q = o % 18;
      int tap = q >> 1, co0 = (q & 1) * 64;
      const unsigned short* g =
          wt + ((long)(tap * 128 + co0 + lane)) * CIN + cic * 16 + p * 8;
      gl_lds16(g, &wt_tile[(size_t)(p * WPL + tap * 128 + co0) * 8]);
    }
    __syncthreads();

    const size_t ibase = (size_t)(kh * IPL) * 8;
    const size_t wbase = (size_t)(kh * WPL) * 8;
#pragma unroll
    for (int ky = 0; ky < 3; ++ky) {
      const int hy = ky + rowoff;
#pragma unroll
      for (int kx = 0; kx < 3; ++kx) {
        const int t = ky * 3 + kx;
        bf16x8 a0 = *(const bf16x8*)(&wt_tile[wbase + (size_t)(t * 128 + wco * 64 + l31) * 8]);
        bf16x8 a1 = *(const bf16x8*)(&wt_tile[wbase + (size_t)(t * 128 + wco * 64 + 32 + l31) * 8]);
        bf16x8 b0 = *(const bf16x8*)(&in_tile[ibase + (size_t)(hy * 130 + p0 + l31 + kx) * 8]);
        bf16x8 b1 = *(const bf16x8*)(&in_tile[ibase + (size_t)(hy * 130 + p0 + 32 + l31 + kx) * 8]);
        acc[0][0] = __builtin_amdgcn_mfma_f32_32x32x16_bf16(a0, b0, acc[0][0], 0, 0, 0);
        acc[0][1] = __builtin_amdgcn_mfma_f32_32x32x16_bf16(a0, b1, acc[0][1], 0, 0, 0);
        acc[1][0] = __builtin_amdgcn_mfma_f32_32x32x16_bf16(a1, b0, acc[1][0], 0, 0, 0);
        acc[1][1] = __builtin_amdgcn_mfma_f32_32x32x16_bf16(a1, b1, acc[1][1], 0, 0, 0);
      }
    }
  }

  // epilogue: bias + leaky. D layout: col(px)=lane&31, row(co)=(r&3)+8*(r>>2)+4*kh
  const int gyo = y0 + rowoff;
#pragma unroll
  for (int fc = 0; fc < 2; ++fc) {
#pragma unroll
    for (int fp = 0; fp < 2; ++fp) {
      const int px = p0 + fp * 32 + l31;
      if constexpr (!OUT_NCHW) {
#pragma unroll
        for (int rg = 0; rg < 4; ++rg) {
          const int co0 = wco * 64 + fc * 32 + rg * 8 + kh * 4;
          unsigned short pk[4];
#pragma unroll
          for (int q = 0; q < 4; ++q) {
            float v = acc[fc][fp][rg * 4 + q] + sb[co0 + q];
            v = v > 0.f ? v : 0.01f * v;
            pk[q] = f2bf(v);
          }
          uint2 o;
          o.x = (unsigned)pk[0] | ((unsigned)pk[1] << 16);
          o.y = (unsigned)pk[2] | ((unsigned)pk[3] << 16);
          *(uint2*)(&dst_bf16[((long)(b * 128 + gyo) * 130 + px + 1) * 128 + co0]) = o;
        }
      } else {
#pragma unroll
        for (int r = 0; r < 16; ++r) {
          const int co = wco * 64 + fc * 32 + (r & 3) + 8 * (r >> 2) + 4 * kh;
          float v = acc[fc][fp][r] + sb[co];
          v = v > 0.f ? v : 0.01f * v;
          dst_f32[((long)(b * 128 + co) << 14) + (gyo << 7) + px] = v;
        }
      }
    }
  }
  if constexpr (!OUT_NCHW) {  // zero x-pad cols 0,129 of this block's 2 rows
    if (tid < 64) {
      int row = tid >> 5, colsel = (tid >> 4) & 1, k = tid & 15;
      long col = colsel * 129L;
      *(uint4*)(&dst_bf16[((long)(b * 128 + y0 + row) * 130 + col) * 128 + k * 8]) =
          make_uint4(0, 0, 0, 0);
    }
  }
}

// ---------------- 1x1 conv to 2 classes + entropy map + unob --------------
__global__ __launch_bounds__(128) void ds_amap(
    const float* __restrict__ h, const float* __restrict__ wds,
    const int* __restrict__ tar, float* __restrict__ ds,
    float* __restrict__ amap) {
  __shared__ float w0[128], w1[128];
  int row = blockIdx.x;
  int b = row >> 7, y = row & 127;
  int px = threadIdx.x;
  w0[px] = wds[px];
  w1[px] = wds[128 + px];
  __syncthreads();
  const float* hp = h + (long)b * 128 * 16384 + y * 128 + px;
  float a0 = 0.f, a1 = 0.f;
#pragma unroll 16
  for (int c = 0; c < 128; ++c) {
    float v = hp[(long)c * 16384];
    a0 += w0[c] * v;
    a1 += w1[c] * v;
  }
  ds[((long)b * 2) * 16384 + y * 128 + px] = a0;
  ds[((long)b * 2 + 1) * 16384 + y * 128 + px] = a1;
  float m = fmaxf(a0, a1);
  float e0 = expf(a0 - m), e1 = expf(a1 - m);
  float s = e0 + e1;
  float p0 = e0 / s, p1 = e1 / s;
  float ent = -(p0 * log2f(p0 + 1e-6f) + p1 * log2f(p1 + 1e-6f));
  float un = ent >= 0.001f ? 1.f : 0.f;
  float pro = 1.f;
  const int* tb = tar + (long)b * 16384;
  if (y > 0 && y < 127 && px > 0 && px < 127) {
    int c = tb[y * 128 + px];
    if (c != 0) {
      int nb = tb[(y - 1) * 128 + px] + tb[(y + 1) * 128 + px] +
               tb[y * 128 + px - 1] + tb[y * 128 + px + 1];
      if (4 * c != nb) pro = 0.f;
    }
  }
  amap[(long)row * 128 + px] = un * pro;
}

extern "C" void kernel_launch(void* const* d_in, const int* in_sizes, int n_in,
                              void* d_out, int out_size, void* d_ws, size_t ws_size,
                              hipStream_t stream) {
  const float* x    = (const float*)d_in[0];
  const float* skip = (const float*)d_in[1];
  const int*   tar  = (const int*)d_in[2];
  const float* W1   = (const float*)d_in[3];
  const float* b1   = (const float*)d_in[4];
  const float* W2   = (const float*)d_in[5];
  const float* b2   = (const float*)d_in[6];
  const float* Wds  = (const float*)d_in[7];

  float* out_h  = (float*)d_out;            // 16777216 f32 (h, NCHW)
  float* out_ds = out_h + 16777216;         // 262144 f32
  float* out_am = out_ds + 262144;          // 131072 f32

  // ws: W1b | W2b | zp | (1MB) h1 (padded NHWC bf16 [8][128][130][128])
  unsigned short* W1b = (unsigned short*)d_ws;             // 589,824 B
  unsigned short* W2b = W1b + 294912;                      // 294,912 B
  unsigned short* zp  = W2b + 147456;                      // 8,192 B zeroed
  unsigned short* h1  = (unsigned short*)((char*)d_ws + (1u << 20));

  // h0: padded NHWC bf16 [8][128][130][256] = 68.2MB, lives in d_out (68.7MB);
  // fully dead before conv2 overwrites d_out with h.
  unsigned short* h0 = (unsigned short*)d_out;

  convert_weights<<<1729, 256, 0, stream>>>(W1, W2, W1b, W2b, zp);
  transpose_to_bf16<<<1024, 256, 0, stream>>>(x, h0, 0);
  transpose_to_bf16<<<1024, 256, 0, stream>>>(skip, h0, 128);
  conv3x3<256, false><<<512, 512, 0, stream>>>(h0, W1b, b1, zp, h1, nullptr);
  conv3x3<128, true><<<512, 512, 0, stream>>>(h1, W2b, b2, zp, nullptr, out_h);
  ds_amap<<<1024, 128, 0, stream>>>(out_h, Wds, tar, out_ds, out_am);
}